// Round 1
// baseline (1530.084 us; speedup 1.0000x reference)
//
#include <hip/hip_runtime.h>
#include <math.h>

#define T_LEN 3000
#define HID 64
#define NTHREADS 192
#define CH 128  // x staging chunk (power of 2)

__device__ __forceinline__ float sigmoid_f(float v) {
    // 1/(1+exp(-v)); v_exp_f32 + v_rcp_f32, ~1e-6 rel err
    return __builtin_amdgcn_rcpf(1.0f + __expf(-v));
}
__device__ __forceinline__ float tanh_f(float v) {
    // tanh(v) = 2*sigmoid(2v) - 1; saturates correctly for |v| large
    return fmaf(2.0f, __builtin_amdgcn_rcpf(1.0f + __expf(-2.0f * v)), -1.0f);
}

__global__ __launch_bounds__(NTHREADS, 1) void gru_fused(
    const float* __restrict__ x,     // (B, T, 1)
    const float* __restrict__ W_ih,  // (192, 1)
    const float* __restrict__ W_hh,  // (192, 64)
    const float* __restrict__ b_ih,  // (192,)
    const float* __restrict__ b_hh,  // (192,)
    const float* __restrict__ W_fc,  // (1, 64)
    const float* __restrict__ b_fc,  // (1,)
    float* __restrict__ out)         // (B,)
{
    const int b    = blockIdx.x;
    const int tid  = threadIdx.x;    // 0..191 == gate row g
    const int wave = tid >> 6;       // 0: r-gate, 1: z-gate, 2: n-gate
    const int lane = tid & 63;       // hidden unit index within gate

    __shared__ __align__(16) float h_lds[HID];
    __shared__ float r_lds[HID];
    __shared__ float z_lds[HID];
    __shared__ float x_lds[CH];

    // ---- one-time preload: W_hh row g into 64 VGPRs (16 x float4) ----
    float4 w[16];
    const float4* wrow = reinterpret_cast<const float4*>(W_hh) + tid * 16;
#pragma unroll
    for (int i = 0; i < 16; ++i) w[i] = wrow[i];

    const float wih = W_ih[tid];
    const float bih = b_ih[tid];
    const float bhh = b_hh[tid];

    // init h = 0; stage first x chunk
    if (tid < HID) h_lds[tid] = 0.0f;
    if (tid < CH)  x_lds[tid] = x[(long)b * T_LEN + tid];
    float hreg = 0.0f;  // wave2 lane k persistently holds h[k]
    __syncthreads();

    const float4* h4 = reinterpret_cast<const float4*>(h_lds);

    for (int t = 0; t < T_LEN; ++t) {
        // ---- matvec: acc = W_hh[g] . h  (broadcast LDS reads, 4 acc chains) ----
        float p0 = 0.f, p1 = 0.f, p2 = 0.f, p3 = 0.f;
#pragma unroll
        for (int i = 0; i < 16; i += 4) {
            float4 h0 = h4[i + 0], h1 = h4[i + 1], h2 = h4[i + 2], h3 = h4[i + 3];
            p0 = fmaf(w[i + 0].x, h0.x, p0); p0 = fmaf(w[i + 0].y, h0.y, p0);
            p0 = fmaf(w[i + 0].z, h0.z, p0); p0 = fmaf(w[i + 0].w, h0.w, p0);
            p1 = fmaf(w[i + 1].x, h1.x, p1); p1 = fmaf(w[i + 1].y, h1.y, p1);
            p1 = fmaf(w[i + 1].z, h1.z, p1); p1 = fmaf(w[i + 1].w, h1.w, p1);
            p2 = fmaf(w[i + 2].x, h2.x, p2); p2 = fmaf(w[i + 2].y, h2.y, p2);
            p2 = fmaf(w[i + 2].z, h2.z, p2); p2 = fmaf(w[i + 2].w, h2.w, p2);
            p3 = fmaf(w[i + 3].x, h3.x, p3); p3 = fmaf(w[i + 3].y, h3.y, p3);
            p3 = fmaf(w[i + 3].z, h3.z, p3); p3 = fmaf(w[i + 3].w, h3.w, p3);
        }
        const float acc = ((p0 + p1) + (p2 + p3)) + bhh;       // W_hh[g].h + b_hh[g]
        const float xt  = x_lds[t & (CH - 1)];
        const float gi  = fmaf(xt, wih, bih);                  // x_t*W_ih[g] + b_ih[g]

        if (wave == 0) {
            r_lds[lane] = sigmoid_f(acc + gi);
        } else if (wave == 1) {
            z_lds[lane] = sigmoid_f(acc + gi);
        }
        __syncthreads();

        if (wave == 2) {
            const float rv = r_lds[lane];
            const float zv = z_lds[lane];
            const float n  = tanh_f(fmaf(rv, acc, gi));        // tanh(gi_n + r*(Whn.h + bhn))
            hreg = fmaf(zv, hreg - n, n);                      // (1-z)*n + z*h
            h_lds[lane] = hreg;
        } else {
            // waves 0/1: stage the next x chunk while wave2 finishes the step
            const int tn = t + 1;
            if ((tn & (CH - 1)) == 0 && tid < CH) {
                const int tt = tn + tid;
                x_lds[tid] = (tt < T_LEN) ? x[(long)b * T_LEN + tt] : 0.0f;
            }
        }
        __syncthreads();
    }

    // ---- epilogue: out[b] = h . W_fc + b_fc (wave2 shuffle reduction) ----
    if (wave == 2) {
        float v = hreg * W_fc[lane];
#pragma unroll
        for (int off = 32; off > 0; off >>= 1) v += __shfl_down(v, off);
        if (lane == 0) out[b] = v + b_fc[0];
    }
}

extern "C" void kernel_launch(void* const* d_in, const int* in_sizes, int n_in,
                              void* d_out, int out_size, void* d_ws, size_t ws_size,
                              hipStream_t stream) {
    const float* x    = (const float*)d_in[0];
    const float* W_ih = (const float*)d_in[1];
    const float* W_hh = (const float*)d_in[2];
    const float* b_ih = (const float*)d_in[3];
    const float* b_hh = (const float*)d_in[4];
    const float* W_fc = (const float*)d_in[5];
    const float* b_fc = (const float*)d_in[6];
    float* out = (float*)d_out;

    const int B = 256;  // in_sizes[0] = B*T = 768000, T = 3000
    gru_fused<<<B, NTHREADS, 0, stream>>>(x, W_ih, W_hh, b_ih, b_hh, W_fc, b_fc, out);
}